// Round 8
// baseline (608.654 us; speedup 1.0000x reference)
//
#include <hip/hip_runtime.h>

typedef short short8 __attribute__((ext_vector_type(8)));
typedef float floatx4 __attribute__((ext_vector_type(4)));

#define BK 16   // cols per bucket (one block owns one bucket exclusively)

__device__ __forceinline__ unsigned short f2bf(float f) {
  unsigned int u = __float_as_uint(f);
  u += 0x7FFFu + ((u >> 16) & 1u);   // RNE
  return (unsigned short)(u >> 16);
}

#if __has_builtin(__builtin_amdgcn_cvt_pk_bf16_f32)
typedef __bf16 bf16x2_t __attribute__((ext_vector_type(2)));
__device__ __forceinline__ unsigned int pk2bf(float lo, float hi) {
  bf16x2_t v = __builtin_amdgcn_cvt_pk_bf16_f32(lo, hi);
  return __builtin_bit_cast(unsigned int, v);
}
#else
__device__ __forceinline__ unsigned int pk2bf(float lo, float hi) {
  return (unsigned)f2bf(lo) | ((unsigned)f2bf(hi) << 16);
}
#endif

__device__ __forceinline__ float silu(float h) {
  return h * __builtin_amdgcn_rcpf(1.f + __expf(-h));
}

// ---------------------------------------------------------------------------
// Fused setup: job0 bucket histogram (hist pre-zeroed via memset) | job1
// weight repack.  wbuf (ushort): [0,16384) W1x frags [nt=8][ks=4][lane=64][j=8]
// ; [16384,32768) W1p; [32768,40960) W2x [nt=4][...].  val = W[k][n],
// k = ks*32+(lane>>4)*8+j, n = nt*16+(lane&15). A/B-operand layouts coincide.
// ---------------------------------------------------------------------------
__global__ __launch_bounds__(256) void k_setup(
    const int* __restrict__ colp, int E, int* __restrict__ hist,
    const float* __restrict__ W1x, const float* __restrict__ W1p,
    const float* __restrict__ W2x, unsigned short* __restrict__ wbuf,
    int b1)
{
  int blk = blockIdx.x, t = threadIdx.x;
  if (blk < b1) {                                   // job0: bucket histogram
    int i = (blk * 256 + t) * 4;
    if (i + 4 <= E) {
      int4 c = *(const int4*)(colp + i);
      atomicAdd(&hist[c.x >> 4], 1); atomicAdd(&hist[c.y >> 4], 1);
      atomicAdd(&hist[c.z >> 4], 1); atomicAdd(&hist[c.w >> 4], 1);
    } else {
      for (int k = i; k < E; ++k) atomicAdd(&hist[colp[k] >> 4], 1);
    }
  } else {                                          // job1: weight repack
    int i = (blk - b1) * 256 + t;
    if (i >= 40960) return;
    int jj = i & 7, lane = (i >> 3) & 63, ks = (i >> 9) & 3;
    int k = ks*32 + (lane >> 4)*8 + jj;
    float v;
    if (i < 32768) {
      const float* W = (i < 16384) ? W1x : W1p;
      int nt = (i >> 11) & 7;
      v = W[k*128 + nt*16 + (lane & 15)];
    } else {
      int nt = (i >> 11) & 3;
      v = W2x[k*64 + nt*16 + (lane & 15)];
    }
    wbuf[i] = f2bf(v);
  }
}

// ---------------------------------------------------------------------------
// Per-node layer-1 partials:
//   Ar[n][h] = x[n]·W1[0:64,h] + b1[h]   (row side, bias folded)
//   Ac[n][h] = x[n]·W1[64:128,h]         (col side)
// both MLPs, bf16 packed per h: uint[n*128+h] = (x | p<<16).
// Orientation: A = weight frags (A[m=h][k]), B = x-tile (B[k][n=node])
// -> D[h][node]: lane lc = node, quad*4+r = h-sub -> each lane stores ONE
// aligned uint4 (4 consecutive h) per (mw,ti,table): 16 uint4 stores/thread.
// ---------------------------------------------------------------------------
__global__ __launch_bounds__(256) void k_nodeA(
    const float* __restrict__ x, const unsigned short* __restrict__ wbuf,
    const float* __restrict__ b1x, const float* __restrict__ b1p, int N,
    unsigned int* __restrict__ Ar, unsigned int* __restrict__ Ac)
{
  __shared__ __align__(16) unsigned short xt[64][72];
  const int t = threadIdx.x, n0 = blockIdx.x * 64;
  const int wv = t >> 6, lane = t & 63, quad = lane >> 4, lc = lane & 15;

  {  // stage x tile (bf16)
    int nd = t >> 2, p = t & 3;
    int n = n0 + nd;
    uint4 o0, o1;
    if (n < N) {
      const float4* xp = (const float4*)(x + (size_t)n*64 + p*16);
      float4 a = xp[0], b = xp[1], c = xp[2], d = xp[3];
      o0 = make_uint4(pk2bf(a.x,a.y), pk2bf(a.z,a.w), pk2bf(b.x,b.y), pk2bf(b.z,b.w));
      o1 = make_uint4(pk2bf(c.x,c.y), pk2bf(c.z,c.w), pk2bf(d.x,d.y), pk2bf(d.z,d.w));
    } else {
      o0 = o1 = make_uint4(0u,0u,0u,0u);
    }
    *(uint4*)&xt[nd][p*16]     = o0;
    *(uint4*)&xt[nd][p*16 + 8] = o1;
  }

  const short8* __restrict__ w1x_f = (const short8*)wbuf;
  const short8* __restrict__ w1p_f = (const short8*)(wbuf + 16384);
  short8 fxr[2][2], fxc[2][2], fpr[2][2], fpc[2][2];
  float bxv[2][4], bpv[2][4];
  #pragma unroll
  for (int ti = 0; ti < 2; ++ti) {
    int nt = wv + 4*ti;
    #pragma unroll
    for (int k2 = 0; k2 < 2; ++k2) {
      fxr[ti][k2] = w1x_f[(nt*4 + k2)*64 + lane];
      fxc[ti][k2] = w1x_f[(nt*4 + 2 + k2)*64 + lane];
      fpr[ti][k2] = w1p_f[(nt*4 + k2)*64 + lane];
      fpc[ti][k2] = w1p_f[(nt*4 + 2 + k2)*64 + lane];
    }
    #pragma unroll
    for (int r = 0; r < 4; ++r) {
      bxv[ti][r] = b1x[nt*16 + quad*4 + r];
      bpv[ti][r] = b1p[nt*16 + quad*4 + r];
    }
  }
  __syncthreads();

  #pragma unroll 1
  for (int mw = 0; mw < 4; ++mw) {
    // B-operand: B[k][n=lc] = x[node n][k]
    short8 b0 = *(const short8*)&xt[mw*16 + lc][quad*8];       // k 0..31
    short8 b1f = *(const short8*)&xt[mw*16 + lc][32 + quad*8]; // k 32..63
    const int nd = n0 + mw*16 + lc;
    #pragma unroll
    for (int ti = 0; ti < 2; ++ti) {
      floatx4 xr = {0,0,0,0}, xc = {0,0,0,0}, pr = {0,0,0,0}, pc = {0,0,0,0};
      xr = __builtin_amdgcn_mfma_f32_16x16x32_bf16(fxr[ti][0], b0,  xr, 0,0,0);
      xr = __builtin_amdgcn_mfma_f32_16x16x32_bf16(fxr[ti][1], b1f, xr, 0,0,0);
      xc = __builtin_amdgcn_mfma_f32_16x16x32_bf16(fxc[ti][0], b0,  xc, 0,0,0);
      xc = __builtin_amdgcn_mfma_f32_16x16x32_bf16(fxc[ti][1], b1f, xc, 0,0,0);
      pr = __builtin_amdgcn_mfma_f32_16x16x32_bf16(fpr[ti][0], b0,  pr, 0,0,0);
      pr = __builtin_amdgcn_mfma_f32_16x16x32_bf16(fpr[ti][1], b1f, pr, 0,0,0);
      pc = __builtin_amdgcn_mfma_f32_16x16x32_bf16(fpc[ti][0], b0,  pc, 0,0,0);
      pc = __builtin_amdgcn_mfma_f32_16x16x32_bf16(fpc[ti][1], b1f, pc, 0,0,0);
      if (nd < N) {
        const int hbase = (wv + 4*ti)*16 + quad*4;
        uint4 ur = make_uint4(pk2bf(xr[0]+bxv[ti][0], pr[0]+bpv[ti][0]),
                              pk2bf(xr[1]+bxv[ti][1], pr[1]+bpv[ti][1]),
                              pk2bf(xr[2]+bxv[ti][2], pr[2]+bpv[ti][2]),
                              pk2bf(xr[3]+bxv[ti][3], pr[3]+bpv[ti][3]));
        uint4 uc = make_uint4(pk2bf(xc[0], pc[0]), pk2bf(xc[1], pc[1]),
                              pk2bf(xc[2], pc[2]), pk2bf(xc[3], pc[3]));
        *(uint4*)(Ar + (size_t)nd*128 + hbase) = ur;
        *(uint4*)(Ac + (size_t)nd*128 + hbase) = uc;
      }
    }
  }
}

// ---------------------------------------------------------------------------
// Single-block exclusive scan over nb bucket counts; writes boff[0..nb]
// (with total sentinel) and turns hist into the scatter cursor.
// ---------------------------------------------------------------------------
#define SCAN_C 13
__global__ __launch_bounds__(256) void k_scan(
    int* __restrict__ hist, int nb, int* __restrict__ boff) {
  __shared__ int wtot[4], wexc[4];
  const int t = threadIdx.x, lane = t & 63, w = t >> 6;
  const int base = t * SCAN_C;
  int v[SCAN_C]; int s = 0;
  #pragma unroll
  for (int j = 0; j < SCAN_C; ++j) {
    int idx = base + j;
    v[j] = (idx < nb) ? hist[idx] : 0;
    s += v[j];
  }
  int inc = s;
  #pragma unroll
  for (int st = 1; st < 64; st <<= 1) {
    int u = __shfl_up(inc, st, 64);
    if (lane >= st) inc += u;
  }
  if (lane == 63) wtot[w] = inc;
  __syncthreads();
  if (t == 0) {
    int a = 0;
    #pragma unroll
    for (int i = 0; i < 4; ++i) { wexc[i] = a; a += wtot[i]; }
  }
  __syncthreads();
  int run = wexc[w] + (inc - s);
  #pragma unroll
  for (int j = 0; j < SCAN_C; ++j) {
    int idx = base + j;
    if (idx < nb) { boff[idx] = run; hist[idx] = run; run += v[j]; }
  }
  if (t == 255) boff[nb] = run;
}

// ---------------------------------------------------------------------------
// Scatter edges into bucket-contiguous regions, packed uint (row<<16|col).
// ---------------------------------------------------------------------------
__global__ __launch_bounds__(256) void k_scatter(
    const int* __restrict__ row, const int* __restrict__ col, int E,
    int* __restrict__ cursor, unsigned int* __restrict__ sedge) {
  int i = blockIdx.x * 256 + threadIdx.x;
  if (i < E) {
    int c = col[i];
    int p = atomicAdd(&cursor[c >> 4], 1);
    sedge[p] = ((unsigned)row[i] << 16) | (unsigned)c;
  }
}

// ---------------------------------------------------------------------------
// Main kernel (bucketed): block b owns cols [b*16, b*16+16) exclusively.
// Loops over its edges in 64-edge tiles:
//   layer1: h = Ar[row] + Ac[col] + dsq*W1[128] (tables bf16, bias in Ar),
//           silu -> H_lds (bf16); phi_p dot -> wsum.
//   layer2: MFMA W2x^T @ H^T -> LDS fp32 accumulate (atomicAdd on shared,
//           ~2-way collisions); phi_p -> LDS accumulate.
// Flush once per block with plain coalesced stores — no global atomics,
// no d_out pre-zeroing needed, no segmentation shuffles.
// ---------------------------------------------------------------------------
__global__ __launch_bounds__(256) void mp_main(
    const float* __restrict__ pos,
    const unsigned int* __restrict__ sedge, const int* __restrict__ boff,
    int N,
    const unsigned int* __restrict__ Ar, const unsigned int* __restrict__ Ac,
    const float* __restrict__ W1x, const float* __restrict__ W1p,
    const float* __restrict__ b2x, const float* __restrict__ W2p,
    const float* __restrict__ b2p,
    const unsigned short* __restrict__ wbuf,
    float* __restrict__ out_x, float* __restrict__ out_pos)
{
  __shared__ __align__(16) unsigned short H_lds[64][136];  // 17408 B
  __shared__ __align__(16) float accx[BK][68];             // 4352 B
  __shared__ float accp[BK][4];                            // 256 B
  __shared__ unsigned int esh_rc[64];
  __shared__ float esh_dsq[64];
  __shared__ float rel_lds[64][3];
  __shared__ int   col_sh[64];
  __shared__ float wsum[4][64];

  const int t    = threadIdx.x;
  const int wv   = t >> 6;
  const int lane = t & 63;
  const int quad = lane >> 4;
  const int lc   = lane & 15;

  const int b  = blockIdx.x;
  const int c0 = b * BK;
  const int es = boff[b], ee = boff[b + 1];
  const int ntiles = (ee - es + 63) >> 6;

  // zero LDS accumulators
  #pragma unroll
  for (int i = t; i < BK*68; i += 256) ((float*)accx)[i] = 0.f;
  if (t < BK*4) ((float*)accp)[t] = 0.f;

  // per-block constants
  const short8* __restrict__ w2x_f = (const short8*)(wbuf + 32768);
  short8 a2w[4];
  #pragma unroll
  for (int ks = 0; ks < 4; ++ks) a2w[ks] = w2x_f[(wv*4 + ks)*64 + lane];

  float w1xd[2][4], w1pd[2][4], wp2[2][4], b2xr[4];
  #pragma unroll
  for (int ti = 0; ti < 2; ++ti)
    #pragma unroll
    for (int r = 0; r < 4; ++r) {
      int h = (wv + 4*ti)*16 + quad*4 + r;
      w1xd[ti][r] = W1x[16384 + h];     // dist^2 row (row 128 of [129][128])
      w1pd[ti][r] = W1p[16384 + h];
      wp2[ti][r]  = W2p[h];
    }
  #pragma unroll
  for (int r = 0; r < 4; ++r) b2xr[r] = b2x[wv*16 + quad*4 + r];
  const float b2ps = b2p[0];

  #pragma unroll 1
  for (int tile = 0; tile < ntiles; ++tile) {
    __syncthreads();               // B1: prev tile fully consumed

    if (t < 64) {                  // phase 1: per-edge scalars
      int e = es + tile*64 + t;
      unsigned rc = 0u; int cl = -1;
      float rp0 = 0.f, rp1 = 0.f, rp2 = 0.f, dsq = 0.f;
      if (e < ee) {
        rc = sedge[e];
        int r = rc >> 16, c = rc & 0xffffu;
        cl = c - c0;
        float pr0 = pos[r*3+0], pr1 = pos[r*3+1], pr2 = pos[r*3+2];
        float pc0 = pos[c*3+0], pc1 = pos[c*3+1], pc2 = pos[c*3+2];
        rp0 = pr0 - pc0; rp1 = pr1 - pc1; rp2 = pr2 - pc2;
        dsq = rp0*rp0 + rp1*rp1 + rp2*rp2;
      }
      esh_rc[t] = rc; esh_dsq[t] = dsq;
      rel_lds[t][0] = rp0; rel_lds[t][1] = rp1; rel_lds[t][2] = rp2;
      col_sh[t] = cl;
    }
    __syncthreads();               // B2: edge data ready

    // ---- layer 1: table gather + silu -> H_lds; phi_p dot -> wsum ----
    #pragma unroll 2
    for (int et = 0; et < 4; ++et) {
      const int j0 = et*16 + lc;
      const unsigned rc = esh_rc[j0];
      const unsigned row = rc >> 16, colg = rc & 0xffffu;
      const float dsqv = esh_dsq[j0];
      float ps = 0.f;
      #pragma unroll
      for (int ti = 0; ti < 2; ++ti) {
        const int ht = wv + 4*ti;
        const int hb = ht*32 + quad*8;             // ushort offset in node row
        uint4 va = *(const uint4*)((const unsigned short*)Ar + (size_t)row*256 + hb);
        uint4 vc = *(const uint4*)((const unsigned short*)Ac + (size_t)colg*256 + hb);
        float sx[4];
        #pragma unroll
        for (int j = 0; j < 4; ++j) {
          unsigned a = (&va.x)[j], bb = (&vc.x)[j];
          float hx = __uint_as_float(a << 16) + __uint_as_float(bb << 16)
                   + dsqv * w1xd[ti][j];
          float hp = __uint_as_float(a & 0xffff0000u) + __uint_as_float(bb & 0xffff0000u)
                   + dsqv * w1pd[ti][j];
          sx[j] = silu(hx);
          ps += silu(hp) * wp2[ti][j];
        }
        *(uint2*)&H_lds[et*16 + lc][ht*16 + quad*4] =
            make_uint2(pk2bf(sx[0], sx[1]), pk2bf(sx[2], sx[3]));
      }
      ps += __shfl_xor(ps, 16, 64);
      ps += __shfl_xor(ps, 32, 64);
      if (lane < 16) wsum[wv][et*16 + lane] = ps;
    }
    __syncthreads();               // B3: H_lds & wsum ready

    // ---- layer 2: MFMA -> LDS fp32 accumulate ----
    #pragma unroll 2
    for (int et = 0; et < 4; ++et) {
      floatx4 acc = {0,0,0,0};
      #pragma unroll
      for (int ks = 0; ks < 4; ++ks) {
        short8 bb = *(const short8*)&H_lds[et*16 + lc][ks*32 + quad*8];
        acc = __builtin_amdgcn_mfma_f32_16x16x32_bf16(a2w[ks], bb, acc, 0, 0, 0);
      }
      int cl = col_sh[et*16 + lc];
      if (cl >= 0) {
        float* dst = &accx[cl][wv*16 + quad*4];
        atomicAdd(dst + 0, acc[0] + b2xr[0]);
        atomicAdd(dst + 1, acc[1] + b2xr[1]);
        atomicAdd(dst + 2, acc[2] + b2xr[2]);
        atomicAdd(dst + 3, acc[3] + b2xr[3]);
      }
    }

    // ---- phi_p: weight * rel_pos -> LDS accumulate ----
    if (t < 64) {
      int cl = col_sh[t];
      if (cl >= 0) {
        float w = wsum[0][t] + wsum[1][t] + wsum[2][t] + wsum[3][t] + b2ps;
        atomicAdd(&accp[cl][0], w * rel_lds[t][0]);
        atomicAdd(&accp[cl][1], w * rel_lds[t][1]);
        atomicAdd(&accp[cl][2], w * rel_lds[t][2]);
      }
    }
  }
  __syncthreads();

  // ---- flush: plain coalesced stores (block owns these cols) ----
  if (t < 128) {
    int cl = t >> 3, f = (t & 7) * 8;
    int n = c0 + cl;
    if (n < N) {
      float4 v0 = *(float4*)&accx[cl][f];
      float4 v1 = *(float4*)&accx[cl][f + 4];
      *(float4*)(out_x + (size_t)n*64 + f)     = v0;
      *(float4*)(out_x + (size_t)n*64 + f + 4) = v1;
    }
  }
  if (t < BK) {
    int n = c0 + t;
    if (n < N) {
      out_pos[(size_t)n*3 + 0] = accp[t][0];
      out_pos[(size_t)n*3 + 1] = accp[t][1];
      out_pos[(size_t)n*3 + 2] = accp[t][2];
    }
  }
}

extern "C" void kernel_launch(void* const* d_in, const int* in_sizes, int n_in,
                              void* d_out, int out_size, void* d_ws, size_t ws_size,
                              hipStream_t stream) {
  const float* x   = (const float*)d_in[0];
  const float* pos = (const float*)d_in[1];
  const int*   ei  = (const int*)d_in[2];
  const float* W1x = (const float*)d_in[3];
  const float* b1x = (const float*)d_in[4];
  const float* W2x = (const float*)d_in[5];
  const float* b2x = (const float*)d_in[6];
  const float* W1p = (const float*)d_in[7];
  const float* b1p = (const float*)d_in[8];
  const float* W2p = (const float*)d_in[9];
  const float* b2p = (const float*)d_in[10];

  const int E = in_sizes[2] / 2;        // 800000
  const int N = in_sizes[0] / 64;       // 50000
  const int* rowp = ei;
  const int* colp = ei + E;
  float* out_x   = (float*)d_out;
  float* out_pos = out_x + (size_t)N * 64;

  const int nb = (N + BK - 1) / BK;     // 3125 buckets

  // ws layout
  char* ws = (char*)d_ws;
  const size_t tab_one = (size_t)N * 512;              // 25.6 MB per table
  unsigned int*   Ar    = (unsigned int*)ws;
  unsigned int*   Ac    = (unsigned int*)(ws + tab_one);
  unsigned short* wbuf  = (unsigned short*)(ws + 2*tab_one);
  int*  hist  = (int*)(ws + 2*tab_one + 81920);                 // nb ints (cursor after scan)
  int*  boffp = (int*)(ws + 2*tab_one + 81920 + 12544);         // nb+1 ints
  unsigned int* sedge = (unsigned int*)(ws + 2*tab_one + 81920 + 12544 + 12544);

  hipMemsetAsync(hist, 0, (size_t)nb * sizeof(int), stream);

  // fused setup: histogram | weight repack
  const int nb_hist = (E/4 + 255) / 256 + 1;
  k_setup<<<nb_hist + 160, 256, 0, stream>>>(colp, E, hist, W1x, W1p, W2x, wbuf,
                                             nb_hist);

  k_nodeA<<<(N + 63) / 64, 256, 0, stream>>>(x, wbuf, b1x, b1p, N, Ar, Ac);

  k_scan<<<1, 256, 0, stream>>>(hist, nb, boffp);

  k_scatter<<<(E + 255) / 256, 256, 0, stream>>>(rowp, colp, E, hist, sedge);

  mp_main<<<nb, 256, 0, stream>>>(pos, sedge, boffp, N, Ar, Ac,
                                  W1x, W1p, b2x, W2p, b2p, wbuf,
                                  out_x, out_pos);
}